// Round 1
// baseline (165.330 us; speedup 1.0000x reference)
//
#include <hip/hip_runtime.h>

#define BB 16
#define SS 2048
#define DD 64

typedef _Float16 half8 __attribute__((ext_vector_type(8)));
typedef _Float16 half4 __attribute__((ext_vector_type(4)));
typedef float f32x4 __attribute__((ext_vector_type(4)));

// ---------------- setup: K -> f16 copy, V -> f16 transposed [b][d][s] ----------------
__global__ __launch_bounds__(256) void setup_kernel(const float* __restrict__ K,
                                                    const float* __restrict__ V,
                                                    _Float16* __restrict__ Kh,
                                                    _Float16* __restrict__ VT) {
  __shared__ float tile[64][65];
  int b = blockIdx.x >> 5, kt = blockIdx.x & 31;  // 32 tiles of 64 rows
  int tid = threadIdx.x;
  size_t base = ((size_t)b * SS + (size_t)kt * 64) * DD;
  const float4* Kq = (const float4*)(K + base);
  const float4* Vq = (const float4*)(V + base);
  half4* Khq = (half4*)(Kh + base);
#pragma unroll
  for (int it = 0; it < 4; ++it) {
    int i = tid + it * 256;  // quad index 0..1023 over 64x64 tile
    float4 kv = Kq[i];
    half4 h;
    h[0] = (_Float16)kv.x; h[1] = (_Float16)kv.y;
    h[2] = (_Float16)kv.z; h[3] = (_Float16)kv.w;
    Khq[i] = h;
    float4 vv = Vq[i];
    int row = i >> 4, c4 = (i & 15) << 2;
    tile[row][c4 + 0] = vv.x; tile[row][c4 + 1] = vv.y;
    tile[row][c4 + 2] = vv.z; tile[row][c4 + 3] = vv.w;
  }
  __syncthreads();
  int d = tid >> 2, seg = tid & 3;  // 64 d-rows x 4 segments of 16 k
  half8 o0, o1;
#pragma unroll
  for (int j = 0; j < 8; ++j) o0[j] = (_Float16)tile[seg * 16 + j][d];
#pragma unroll
  for (int j = 0; j < 8; ++j) o1[j] = (_Float16)tile[seg * 16 + 8 + j][d];
  _Float16* dst = VT + ((size_t)b * DD + d) * SS + (size_t)kt * 64 + seg * 16;
  *(half8*)dst = o0;
  *(half8*)(dst + 8) = o1;
}

// ---------------- fused attention ----------------
// wg = (b, 16 q rows), 4 waves; wave w owns k in [w*512, w*512+512)
__global__ __launch_bounds__(256, 2) void attn_kernel(const float* __restrict__ Q,
                                                      const _Float16* __restrict__ Kh,
                                                      const _Float16* __restrict__ VT,
                                                      float* __restrict__ ctx_out,
                                                      float* __restrict__ attn_out) {
  __shared__ _Float16 Pl[4][16][520];   // per-wave P (unnormalized, f16), padded stride
  __shared__ float red[2][4][4][4];     // [max/sum][wave][g][j]

  int tid = threadIdx.x;
  int w = tid >> 6;
  int l = tid & 63;
  int g = l >> 4;
  int c = l & 15;
  int b = blockIdx.x >> 7;
  int qb = blockIdx.x & 127;
  size_t qrow0 = (size_t)b * SS + (size_t)qb * 16;

  // Q A-fragments (scale 1/8 folded in): A[m=c][k_d = 32h + 8g + r]
  half8 qa0, qa1;
  {
    const float* Qp = Q + (qrow0 + c) * DD + 8 * g;
    float4 v0 = *(const float4*)(Qp);
    float4 v1 = *(const float4*)(Qp + 4);
    float4 v2 = *(const float4*)(Qp + 32);
    float4 v3 = *(const float4*)(Qp + 36);
    qa0[0] = (_Float16)(v0.x * 0.125f); qa0[1] = (_Float16)(v0.y * 0.125f);
    qa0[2] = (_Float16)(v0.z * 0.125f); qa0[3] = (_Float16)(v0.w * 0.125f);
    qa0[4] = (_Float16)(v1.x * 0.125f); qa0[5] = (_Float16)(v1.y * 0.125f);
    qa0[6] = (_Float16)(v1.z * 0.125f); qa0[7] = (_Float16)(v1.w * 0.125f);
    qa1[0] = (_Float16)(v2.x * 0.125f); qa1[1] = (_Float16)(v2.y * 0.125f);
    qa1[2] = (_Float16)(v2.z * 0.125f); qa1[3] = (_Float16)(v2.w * 0.125f);
    qa1[4] = (_Float16)(v3.x * 0.125f); qa1[5] = (_Float16)(v3.y * 0.125f);
    qa1[6] = (_Float16)(v3.z * 0.125f); qa1[7] = (_Float16)(v3.w * 0.125f);
  }

  // ---- QK^T: 32 tiles of 16x16, dot over d=64 (2 MFMA K=32 steps) ----
  const _Float16* Kb = Kh + ((size_t)b * SS + (size_t)w * 512) * DD;
  f32x4 acc[32];
#pragma unroll
  for (int t = 0; t < 32; ++t) {
    const _Float16* kr = Kb + (t * 16 + c) * DD + 8 * g;  // B[k_d=8g+r][n=c]
    half8 k0 = *(const half8*)(kr);
    half8 k1 = *(const half8*)(kr + 32);
    f32x4 a = {0.f, 0.f, 0.f, 0.f};
    a = __builtin_amdgcn_mfma_f32_16x16x32_f16(qa0, k0, a, 0, 0, 0);
    a = __builtin_amdgcn_mfma_f32_16x16x32_f16(qa1, k1, a, 0, 0, 0);
    acc[t] = a;  // S[q = 4g+j][k = w*512 + t*16 + c]
  }

  // ---- row max (per wave chunk), then cross-wave ----
  float mf[4];
#pragma unroll
  for (int j = 0; j < 4; ++j) {
    float m = acc[0][j];
#pragma unroll
    for (int t = 1; t < 32; ++t) m = fmaxf(m, acc[t][j]);
#pragma unroll
    for (int msk = 1; msk < 16; msk <<= 1) m = fmaxf(m, __shfl_xor(m, msk));
    mf[j] = m;
  }
  if (c == 0) {
#pragma unroll
    for (int j = 0; j < 4; ++j) red[0][w][g][j] = mf[j];
  }
  __syncthreads();
#pragma unroll
  for (int j = 0; j < 4; ++j) {
    float m = red[0][0][g][j];
    m = fmaxf(m, red[0][1][g][j]);
    m = fmaxf(m, red[0][2][g][j]);
    m = fmaxf(m, red[0][3][g][j]);
    mf[j] = m;
  }

  // ---- exp, P->LDS (unnormalized f16), partial row sums ----
  float ls[4] = {0.f, 0.f, 0.f, 0.f};
#pragma unroll
  for (int t = 0; t < 32; ++t) {
#pragma unroll
    for (int j = 0; j < 4; ++j) {
      float p = __expf(acc[t][j] - mf[j]);
      acc[t][j] = p;
      ls[j] += p;
      Pl[w][4 * g + j][t * 16 + c] = (_Float16)p;
    }
  }
#pragma unroll
  for (int j = 0; j < 4; ++j) {
#pragma unroll
    for (int msk = 1; msk < 16; msk <<= 1) ls[j] += __shfl_xor(ls[j], msk);
  }
  if (c == 0) {
#pragma unroll
    for (int j = 0; j < 4; ++j) red[1][w][g][j] = ls[j];
  }
  __syncthreads();
  float il[4];
#pragma unroll
  for (int j = 0; j < 4; ++j) {
    float s = red[1][0][g][j] + red[1][1][g][j] + red[1][2][g][j] + red[1][3][g][j];
    il[j] = 1.0f / s;
  }

  // ---- attention write (normalized, f32) ----
  {
    float* ap = attn_out + (qrow0 + 4 * g) * SS + (size_t)w * 512 + c;
#pragma unroll
    for (int j = 0; j < 4; ++j) {
#pragma unroll
      for (int t = 0; t < 32; ++t) {
        ap[(size_t)j * SS + t * 16] = acc[t][j] * il[j];
      }
    }
  }

  // ---- PV: context partial over this wave's k-chunk ----
  f32x4 cacc[4] = {{0.f, 0.f, 0.f, 0.f}, {0.f, 0.f, 0.f, 0.f},
                   {0.f, 0.f, 0.f, 0.f}, {0.f, 0.f, 0.f, 0.f}};
  const _Float16* Vb = VT + ((size_t)b * DD + c) * SS + (size_t)w * 512;
#pragma unroll
  for (int ks = 0; ks < 16; ++ks) {
    half8 pf = *(const half8*)&Pl[w][c][ks * 32 + 8 * g];  // A[m=c][k=ks*32+8g+r]
#pragma unroll
    for (int dt = 0; dt < 4; ++dt) {
      half8 vf = *(const half8*)(Vb + (size_t)dt * 16 * SS + ks * 32 + 8 * g);
      cacc[dt] = __builtin_amdgcn_mfma_f32_16x16x32_f16(pf, vf, cacc[dt], 0, 0, 0);
    }
  }

  // ---- cross-wave context reduce (alias Pl as f32 buffer, stride 68) ----
  __syncthreads();
  float* cb = (float*)&Pl[0][0][0];
#pragma unroll
  for (int dt = 0; dt < 4; ++dt) {
#pragma unroll
    for (int j = 0; j < 4; ++j) {
      cb[(w * 16 + 4 * g + j) * 68 + dt * 16 + c] = cacc[dt][j] * il[j];
    }
  }
  __syncthreads();
  {
    int e = tid * 4;
    int q = e >> 6, d0 = e & 63;
    float4 s = {0.f, 0.f, 0.f, 0.f};
#pragma unroll
    for (int wv = 0; wv < 4; ++wv) {
      float4 vx = *(const float4*)&cb[(wv * 16 + q) * 68 + d0];
      s.x += vx.x; s.y += vx.y; s.z += vx.z; s.w += vx.w;
    }
    *(float4*)&ctx_out[(qrow0 + q) * DD + d0] = s;
  }
}

extern "C" void kernel_launch(void* const* d_in, const int* in_sizes, int n_in,
                              void* d_out, int out_size, void* d_ws, size_t ws_size,
                              hipStream_t stream) {
  const float* q = (const float*)d_in[0];
  const float* k = (const float*)d_in[1];
  const float* v = (const float*)d_in[2];
  float* ctx = (float*)d_out;
  float* attn = ctx + (size_t)BB * SS * DD;
  _Float16* Kh = (_Float16*)d_ws;                 // [B][S][D] f16, 4 MB
  _Float16* VT = Kh + (size_t)BB * SS * DD;       // [B][D][S] f16, 4 MB
  setup_kernel<<<dim3(BB * 32), dim3(256), 0, stream>>>(k, v, Kh, VT);
  attn_kernel<<<dim3(BB * (SS / 16)), dim3(256), 0, stream>>>(q, Kh, VT, ctx, attn);
}